// Round 3
// baseline (4864.355 us; speedup 1.0000x reference)
//
#include <hip/hip_runtime.h>
#include <hip/hip_bf16.h>

#define N_NODES 50000
#define N_EDGES 1600000
#define TILE    128

typedef __bf16 bf16x8 __attribute__((ext_vector_type(8)));
typedef float  f32x4  __attribute__((ext_vector_type(4)));

static __device__ __forceinline__ bf16x8 ld8(const __bf16* p) {
  return *reinterpret_cast<const bf16x8*>(p);
}
static __device__ __forceinline__ void st8(__bf16* p, bf16x8 v) {
  *reinterpret_cast<bf16x8*>(p) = v;
}
static __device__ __forceinline__ bf16x8 sub8(bf16x8 a, bf16x8 b) {
  bf16x8 r;
#pragma unroll
  for (int j = 0; j < 8; ++j) r[j] = (__bf16)((float)a[j] - (float)b[j]);
  return r;
}

// ---- prep: transpose weights to [n][k] bf16 (B-operand layout) ----
__global__ __launch_bounds__(256) void k_prep_w(
    const float* __restrict__ Wi, const float* __restrict__ Wu,
    const float* __restrict__ Wf,
    __bf16* __restrict__ WiT, __bf16* __restrict__ WuT, __bf16* __restrict__ WfT)
{
  int g = blockIdx.x * 256 + threadIdx.x;
  if (g < 160 * 128) {
    int n = g / 160, k = g % 160;
    WiT[g] = (__bf16)Wi[k * 128 + n];
  } else if (g < 160 * 128 + 128 * 128) {
    int gg = g - 160 * 128;
    int n = gg / 128, k = gg % 128;
    WuT[gg] = (__bf16)Wu[k * 128 + n];
  } else if (g < 160 * 128 + 128 * 128 + 256 * 128) {
    int gg = g - (160 * 128 + 128 * 128);
    int n = gg / 256, k = gg % 256;
    WfT[gg] = (__bf16)Wf[k * 128 + n];
  }
}

// ---- f32 -> bf16 bulk convert (node_feature) ----
__global__ __launch_bounds__(256) void k_cvt(
    const float* __restrict__ in, __bf16* __restrict__ out, long n)
{
  long i = ((long)blockIdx.x * 256 + threadIdx.x) * 8;
  if (i + 8 <= n) {
    f32x4 f0 = *(const f32x4*)(in + i);
    f32x4 f1 = *(const f32x4*)(in + i + 4);
    bf16x8 o;
#pragma unroll
    for (int j = 0; j < 4; ++j) { o[j] = (__bf16)f0[j]; o[4 + j] = (__bf16)f1[j]; }
    st8(out + i, o);
  }
}

// ---- CSR build: histogram of edge_dst ----
__global__ __launch_bounds__(256) void k_hist(
    const int* __restrict__ edst, int* __restrict__ cnt)
{
  int e = blockIdx.x * 256 + threadIdx.x;
  if (e < N_EDGES) atomicAdd(&cnt[edst[e]], 1);
}

// ---- CSR scan level 1: per-1024-tile exclusive scan IN PLACE + block sums ----
__global__ __launch_bounds__(1024) void k_scan1(
    int* __restrict__ cnt, int* __restrict__ bsum, int n)
{
  __shared__ int sm[1024];
  const int tid = threadIdx.x;
  int i = blockIdx.x * 1024 + tid;
  int v = (i < n) ? cnt[i] : 0;
  sm[tid] = v;
  __syncthreads();
  for (int off = 1; off < 1024; off <<= 1) {
    int t = (tid >= off) ? sm[tid - off] : 0;
    __syncthreads();
    sm[tid] += t;
    __syncthreads();
  }
  if (i < n) cnt[i] = sm[tid] - v;          // exclusive, block-local
  if (tid == 1023) bsum[blockIdx.x] = sm[1023];
}

// ---- CSR scan level 2: serial exclusive scan of block sums (49 values) ----
__global__ __launch_bounds__(64) void k_scan2(int* __restrict__ bsum, int nb)
{
  if (threadIdx.x == 0) {
    int acc = 0;
    for (int k = 0; k < nb; ++k) { int t = bsum[k]; bsum[k] = acc; acc += t; }
  }
}

// ---- CSR scan level 3: materialize fill cursors ----
__global__ __launch_bounds__(256) void k_scan3(
    const int* __restrict__ cnt, const int* __restrict__ bsum,
    int* __restrict__ cursor, int n)
{
  int i = blockIdx.x * 256 + threadIdx.x;
  if (i < n) cursor[i] = cnt[i] + bsum[i >> 10];
}

// ---- CSR build: fill incoming-edge lists ----
__global__ __launch_bounds__(256) void k_fill(
    const int* __restrict__ edst, int* __restrict__ cursor, int* __restrict__ eidx)
{
  int e = blockIdx.x * 256 + threadIdx.x;
  if (e < N_EDGES) {
    int p = atomicAdd(&cursor[edst[e]], 1);
    eidx[p] = e;
  }
}

// ---- gather-aggregate: aggbf[n] = sum over incoming edges h[e] ----
// one wave per node; lane-group g (lane>>4) handles edge i+g, 16B/lane rows,
// cross-group shfl reduce at the end.
__global__ __launch_bounds__(256) void k_agg(
    const __bf16* __restrict__ h, const int* __restrict__ cnt,
    const int* __restrict__ bsum, const int* __restrict__ eidx,
    __bf16* __restrict__ aggbf)
{
  const int wave = threadIdx.x >> 6;
  const int node = blockIdx.x * 4 + wave;
  const int lane = threadIdx.x & 63;
  const int g = lane >> 4, c16 = lane & 15;
  const int s = cnt[node] + bsum[node >> 10];
  const int e = (node + 1 < N_NODES) ? (cnt[node + 1] + bsum[(node + 1) >> 10]) : N_EDGES;
  const int deg = e - s;

  float a[8] = {0.f, 0.f, 0.f, 0.f, 0.f, 0.f, 0.f, 0.f};
  if (deg > 0) {
    const int* bucket = eidx + s;
    const int nit = (deg + 3) >> 2;
    int j = g;
    int ecur = bucket[(j < deg) ? j : 0];
    bool vcur = (j < deg);
    for (int it = 0; it < nit; ++it) {
      int jn = j + 4;
      int enext = bucket[(jn < deg) ? jn : 0];   // prefetch next edge index
      bf16x8 v = ld8(h + (long)ecur * 128 + c16 * 8);
#pragma unroll
      for (int k = 0; k < 8; ++k) a[k] += vcur ? (float)v[k] : 0.f;
      ecur = enext; vcur = (jn < deg); j = jn;
    }
  }
#pragma unroll
  for (int k = 0; k < 8; ++k) {
    a[k] += __shfl_xor(a[k], 16, 64);
    a[k] += __shfl_xor(a[k], 32, 64);
  }
  if (g == 0) {
    bf16x8 o;
#pragma unroll
    for (int k = 0; k < 8; ++k) o[k] = (__bf16)a[k];
    st8(aggbf + (long)node * 128 + c16 * 8, o);
  }
}

// ---- init: h0 = relu([nf[src] | ef] @ Wi + bi) ----
__global__ __launch_bounds__(256, 5) void k_init(
    const __bf16* __restrict__ nfbf, const float* __restrict__ ef,
    const int* __restrict__ esrc,
    const __bf16* __restrict__ WiT, const float* __restrict__ bi,
    __bf16* __restrict__ h)
{
  __shared__ __bf16 lds[64 * 136];  // half tile; +8 pad breaks bank conflicts
  const int tid = threadIdx.x;
  const int lane = tid & 63, wave = tid >> 6;
  const int l15 = lane & 15, quad = lane >> 4;
  const int wm = wave >> 1, wn = wave & 1;
  const long base = (long)blockIdx.x * TILE;

  int srcn[4];
#pragma unroll
  for (int ms = 0; ms < 4; ++ms)
    srcn[ms] = esrc[base + wm * 64 + ms * 16 + l15];

  f32x4 acc[4][4] = {};
#pragma unroll
  for (int kit = 0; kit < 5; ++kit) {
    const int koff = kit * 32 + quad * 8;
    bf16x8 a[4];
#pragma unroll
    for (int ms = 0; ms < 4; ++ms) {
      if (kit < 4) {
        a[ms] = ld8(nfbf + (long)srcn[ms] * 128 + koff);
      } else {
        const float* p = ef + (base + wm * 64 + ms * 16 + l15) * 32 + quad * 8;
        f32x4 f0 = *(const f32x4*)p;
        f32x4 f1 = *(const f32x4*)(p + 4);
        bf16x8 v;
#pragma unroll
        for (int j = 0; j < 4; ++j) { v[j] = (__bf16)f0[j]; v[4 + j] = (__bf16)f1[j]; }
        a[ms] = v;
      }
    }
#pragma unroll
    for (int ns = 0; ns < 4; ++ns) {
      bf16x8 b = ld8(WiT + (wn * 64 + ns * 16 + l15) * 160 + koff);
#pragma unroll
      for (int ms = 0; ms < 4; ++ms)
        acc[ms][ns] = __builtin_amdgcn_mfma_f32_16x16x32_bf16(a[ms], b, acc[ms][ns], 0, 0, 0);
    }
  }
  // two-phase epilogue through half-size LDS
  for (int p = 0; p < 2; ++p) {
    __syncthreads();
    if (wm == p) {
#pragma unroll
      for (int ns = 0; ns < 4; ++ns) {
        const int col = wn * 64 + ns * 16 + l15;
        const float bias = bi[col];
#pragma unroll
        for (int ms = 0; ms < 4; ++ms) {
          const int rl = ms * 16 + quad * 4;
#pragma unroll
          for (int r = 0; r < 4; ++r) {
            float v = acc[ms][ns][r] + bias;
            v = v > 0.f ? v : 0.f;
            lds[(rl + r) * 136 + col] = (__bf16)v;
          }
        }
      }
    }
    __syncthreads();
#pragma unroll
    for (int i = 0; i < 4; ++i) {
      const int c = i * 256 + tid;
      const int rl = c >> 4, k8 = (c & 15) * 8;
      st8(h + (base + p * 64 + rl) * 128 + k8, ld8(lds + rl * 136 + k8));
    }
  }
}

// ---- update: h = relu((agg[src]-h[rev]) @ Wu + bu + h) ----
__global__ __launch_bounds__(256, 5) void k_update(
    const __bf16* __restrict__ aggbf, __bf16* __restrict__ h,
    const int* __restrict__ esrc,
    const __bf16* __restrict__ WuT, const float* __restrict__ bu)
{
  __shared__ __bf16 lds[64 * 136];
  const int tid = threadIdx.x;
  const int lane = tid & 63, wave = tid >> 6;
  const int l15 = lane & 15, quad = lane >> 4;
  const int wm = wave >> 1, wn = wave & 1;
  const long base = (long)blockIdx.x * TILE;

  int srcn[4], rowh[4];
#pragma unroll
  for (int ms = 0; ms < 4; ++ms) {
    const int rm = wm * 64 + ms * 16 + l15;
    srcn[ms] = esrc[base + rm];
    rowh[ms] = rm ^ 1;  // rev(e) = e^1 stays inside the pair-aligned tile
  }

  f32x4 acc[4][4] = {};
#pragma unroll
  for (int kit = 0; kit < 4; ++kit) {
    const int koff = kit * 32 + quad * 8;
    bf16x8 a[4];
#pragma unroll
    for (int ms = 0; ms < 4; ++ms)
      a[ms] = sub8(ld8(aggbf + (long)srcn[ms] * 128 + koff),
                   ld8(h + (base + rowh[ms]) * 128 + koff));
#pragma unroll
    for (int ns = 0; ns < 4; ++ns) {
      bf16x8 b = ld8(WuT + (wn * 64 + ns * 16 + l15) * 128 + koff);
#pragma unroll
      for (int ms = 0; ms < 4; ++ms)
        acc[ms][ns] = __builtin_amdgcn_mfma_f32_16x16x32_bf16(a[ms], b, acc[ms][ns], 0, 0, 0);
    }
  }
  // two-phase epilogue through half-size LDS; residual+relu folded on readback
  for (int p = 0; p < 2; ++p) {
    __syncthreads();
    if (wm == p) {
#pragma unroll
      for (int ns = 0; ns < 4; ++ns) {
        const int col = wn * 64 + ns * 16 + l15;
        const float bias = bu[col];
#pragma unroll
        for (int ms = 0; ms < 4; ++ms) {
          const int rl = ms * 16 + quad * 4;
#pragma unroll
          for (int r = 0; r < 4; ++r)
            lds[(rl + r) * 136 + col] = (__bf16)(acc[ms][ns][r] + bias);
        }
      }
    }
    __syncthreads();
#pragma unroll
    for (int i = 0; i < 4; ++i) {
      const int c = i * 256 + tid;
      const int rl = c >> 4, k8 = (c & 15) * 8;
      const long row = base + p * 64 + rl;
      bf16x8 cv = ld8(lds + rl * 136 + k8);
      bf16x8 hv = ld8(h + row * 128 + k8);
      bf16x8 o;
#pragma unroll
      for (int j = 0; j < 8; ++j) {
        float v = (float)cv[j] + (float)hv[j];
        v = v > 0.f ? v : 0.f;
        o[j] = (__bf16)v;
      }
      st8(h + row * 128 + k8, o);  // in-place: this thread owns this 16B chunk
    }
  }
}

// ---- final: out = relu([nf | agg(h4)] @ Wf + bf) over nodes ----
__global__ __launch_bounds__(256) void k_final(
    const __bf16* __restrict__ nfbf, const __bf16* __restrict__ aggbf,
    const __bf16* __restrict__ WfT, const float* __restrict__ bfb,
    float* __restrict__ out)
{
  const int tid = threadIdx.x;
  const int lane = tid & 63, wave = tid >> 6;
  const int l15 = lane & 15, quad = lane >> 4;
  const int wm = wave >> 1, wn = wave & 1;
  const int base = blockIdx.x * TILE;

  int nodem[4];
#pragma unroll
  for (int ms = 0; ms < 4; ++ms) {
    int nd = base + wm * 64 + ms * 16 + l15;
    nodem[ms] = nd < N_NODES ? nd : (N_NODES - 1);
  }
  f32x4 acc[4][4] = {};
#pragma unroll
  for (int kit = 0; kit < 8; ++kit) {
    const int koff = kit * 32 + quad * 8;
    bf16x8 a[4];
#pragma unroll
    for (int ms = 0; ms < 4; ++ms)
      a[ms] = (kit < 4) ? ld8(nfbf + (long)nodem[ms] * 128 + koff)
                        : ld8(aggbf + (long)nodem[ms] * 128 + (koff - 128));
#pragma unroll
    for (int ns = 0; ns < 4; ++ns) {
      bf16x8 b = ld8(WfT + (wn * 64 + ns * 16 + l15) * 256 + koff);
#pragma unroll
      for (int ms = 0; ms < 4; ++ms)
        acc[ms][ns] = __builtin_amdgcn_mfma_f32_16x16x32_bf16(a[ms], b, acc[ms][ns], 0, 0, 0);
    }
  }
#pragma unroll
  for (int ns = 0; ns < 4; ++ns) {
    const int col = wn * 64 + ns * 16 + l15;
    const float bias = bfb[col];
#pragma unroll
    for (int ms = 0; ms < 4; ++ms) {
      const int r0 = wm * 64 + ms * 16 + quad * 4;
#pragma unroll
      for (int r = 0; r < 4; ++r) {
        const int node = base + r0 + r;
        if (node < N_NODES) {
          float v = acc[ms][ns][r] + bias;
          out[(long)node * 128 + col] = v > 0.f ? v : 0.f;
        }
      }
    }
  }
}

extern "C" void kernel_launch(void* const* d_in, const int* in_sizes, int n_in,
                              void* d_out, int out_size, void* d_ws, size_t ws_size,
                              hipStream_t stream) {
  const float* nf   = (const float*)d_in[0];
  const float* ef   = (const float*)d_in[1];
  const int*   esrc = (const int*)d_in[2];
  const int*   edst = (const int*)d_in[3];
  const float* Wi   = (const float*)d_in[4];
  const float* bi   = (const float*)d_in[5];
  const float* Wu   = (const float*)d_in[6];
  const float* bu   = (const float*)d_in[7];
  const float* Wf   = (const float*)d_in[8];
  const float* bfb  = (const float*)d_in[9];
  float* out = (float*)d_out;

  char* ws = (char*)d_ws;
  __bf16* h      = (__bf16*)(ws);                  // 409,600,000 B
  __bf16* aggbf  = (__bf16*)(ws + 409600000L);     //  12,800,000 B
  __bf16* nfbf   = (__bf16*)(ws + 422400000L);     //  12,800,000 B
  __bf16* WiT    = (__bf16*)(ws + 435200000L);     //      40,960 B
  __bf16* WuT    = (__bf16*)(ws + 435240960L);     //      32,768 B
  __bf16* WfT    = (__bf16*)(ws + 435273728L);     //      65,536 B
  int*    cnt    = (int*)(ws + 435339264L);        //     200,000 B (excl-scan in place)
  int*    cursor = (int*)(ws + 435539264L);        //     200,000 B
  int*    bsum   = (int*)(ws + 435739264L);        //         256 B
  int*    eidx   = (int*)(ws + 435739520L);        //   6,400,000 B  (end 442,139,520)

  const long NV = (long)N_NODES * 128;

  hipLaunchKernelGGL(k_prep_w, dim3(272), dim3(256), 0, stream, Wi, Wu, Wf, WiT, WuT, WfT);
  hipLaunchKernelGGL(k_cvt, dim3(3125), dim3(256), 0, stream, nf, nfbf, NV);
  // CSR build (edge_dst -> incoming edge lists), two-level scan
  hipMemsetAsync(cnt, 0, 200000, stream);
  hipLaunchKernelGGL(k_hist, dim3(N_EDGES / 256), dim3(256), 0, stream, edst, cnt);
  hipLaunchKernelGGL(k_scan1, dim3(49), dim3(1024), 0, stream, cnt, bsum, N_NODES);
  hipLaunchKernelGGL(k_scan2, dim3(1), dim3(64), 0, stream, bsum, 49);
  hipLaunchKernelGGL(k_scan3, dim3(196), dim3(256), 0, stream, cnt, bsum, cursor, N_NODES);
  hipLaunchKernelGGL(k_fill, dim3(N_EDGES / 256), dim3(256), 0, stream, edst, cursor, eidx);

  hipLaunchKernelGGL(k_init, dim3(N_EDGES / TILE), dim3(256), 0, stream,
                     nfbf, ef, esrc, WiT, bi, h);
  for (int t = 0; t < 4; ++t) {
    hipLaunchKernelGGL(k_agg, dim3(N_NODES / 4), dim3(256), 0, stream,
                       h, cnt, bsum, eidx, aggbf);
    hipLaunchKernelGGL(k_update, dim3(N_EDGES / TILE), dim3(256), 0, stream,
                       aggbf, h, esrc, WuT, bu);
  }
  hipLaunchKernelGGL(k_agg, dim3(N_NODES / 4), dim3(256), 0, stream,
                     h, cnt, bsum, eidx, aggbf);
  hipLaunchKernelGGL(k_final, dim3((N_NODES + TILE - 1) / TILE), dim3(256), 0, stream,
                     nfbf, aggbf, WfT, bfb, out);
}

// Round 4
// 2414.966 us; speedup vs baseline: 2.0143x; 2.0143x over previous
//
#include <hip/hip_runtime.h>
#include <hip/hip_bf16.h>

#define N_NODES 50000
#define N_EDGES 1600000
#define TILE    128

typedef __bf16 bf16x8 __attribute__((ext_vector_type(8)));
typedef float  f32x4  __attribute__((ext_vector_type(4)));

static __device__ __forceinline__ bf16x8 ld8(const __bf16* p) {
  return *reinterpret_cast<const bf16x8*>(p);
}
static __device__ __forceinline__ void st8(__bf16* p, bf16x8 v) {
  *reinterpret_cast<bf16x8*>(p) = v;
}

// async global->LDS DMA, 16B per lane; dest = wave-uniform base + lane*16
static __device__ __forceinline__ void async16(const void* g, void* l) {
  auto gp = (const __attribute__((address_space(1))) unsigned int*)(unsigned long long)g;
  auto lp = (__attribute__((address_space(3))) unsigned int*)(unsigned int)(unsigned long long)l;
  __builtin_amdgcn_global_load_lds(gp, lp, 16, 0, 0);
}

// ---- prep: transpose weights to [n][k] bf16 (B-operand layout) ----
__global__ __launch_bounds__(256) void k_prep_w(
    const float* __restrict__ Wi, const float* __restrict__ Wu,
    const float* __restrict__ Wf,
    __bf16* __restrict__ WiT, __bf16* __restrict__ WuT, __bf16* __restrict__ WfT)
{
  int g = blockIdx.x * 256 + threadIdx.x;
  if (g < 160 * 128) {
    int n = g / 160, k = g % 160;
    WiT[g] = (__bf16)Wi[k * 128 + n];
  } else if (g < 160 * 128 + 128 * 128) {
    int gg = g - 160 * 128;
    int n = gg / 128, k = gg % 128;
    WuT[gg] = (__bf16)Wu[k * 128 + n];
  } else if (g < 160 * 128 + 128 * 128 + 256 * 128) {
    int gg = g - (160 * 128 + 128 * 128);
    int n = gg / 256, k = gg % 256;
    WfT[gg] = (__bf16)Wf[k * 128 + n];
  }
}

// ---- f32 -> bf16 bulk convert ----
__global__ __launch_bounds__(256) void k_cvt(
    const float* __restrict__ in, __bf16* __restrict__ out, long n)
{
  long i = ((long)blockIdx.x * 256 + threadIdx.x) * 8;
  if (i + 8 <= n) {
    f32x4 f0 = *(const f32x4*)(in + i);
    f32x4 f1 = *(const f32x4*)(in + i + 4);
    bf16x8 o;
#pragma unroll
    for (int j = 0; j < 4; ++j) { o[j] = (__bf16)f0[j]; o[4 + j] = (__bf16)f1[j]; }
    st8(out + i, o);
  }
}

// ---- CSR build ----
__global__ __launch_bounds__(256) void k_hist(
    const int* __restrict__ edst, int* __restrict__ cnt)
{
  int e = blockIdx.x * 256 + threadIdx.x;
  if (e < N_EDGES) atomicAdd(&cnt[edst[e]], 1);
}

__global__ __launch_bounds__(1024) void k_scan1(
    int* __restrict__ cnt, int* __restrict__ bsum, int n)
{
  __shared__ int sm[1024];
  const int tid = threadIdx.x;
  int i = blockIdx.x * 1024 + tid;
  int v = (i < n) ? cnt[i] : 0;
  sm[tid] = v;
  __syncthreads();
  for (int off = 1; off < 1024; off <<= 1) {
    int t = (tid >= off) ? sm[tid - off] : 0;
    __syncthreads();
    sm[tid] += t;
    __syncthreads();
  }
  if (i < n) cnt[i] = sm[tid] - v;
  if (tid == 1023) bsum[blockIdx.x] = sm[1023];
}

__global__ __launch_bounds__(64) void k_scan2(int* __restrict__ bsum, int nb)
{
  if (threadIdx.x == 0) {
    int acc = 0;
    for (int k = 0; k < nb; ++k) { int t = bsum[k]; bsum[k] = acc; acc += t; }
  }
}

__global__ __launch_bounds__(256) void k_scan3(
    const int* __restrict__ cnt, const int* __restrict__ bsum,
    int* __restrict__ cursor, int n)
{
  int i = blockIdx.x * 256 + threadIdx.x;
  if (i < n) cursor[i] = cnt[i] + bsum[i >> 10];
}

__global__ __launch_bounds__(256) void k_fill(
    const int* __restrict__ edst, int* __restrict__ cursor, int* __restrict__ eidx)
{
  int e = blockIdx.x * 256 + threadIdx.x;
  if (e < N_EDGES) {
    int p = atomicAdd(&cursor[edst[e]], 1);
    eidx[p] = e;
  }
}

// ---- gather-aggregate: aggbf[n] = sum over incoming edges h[e] ----
__global__ __launch_bounds__(256) void k_agg(
    const __bf16* __restrict__ h, const int* __restrict__ cnt,
    const int* __restrict__ bsum, const int* __restrict__ eidx,
    __bf16* __restrict__ aggbf)
{
  const int wave = threadIdx.x >> 6;
  const int node = blockIdx.x * 4 + wave;
  const int lane = threadIdx.x & 63;
  const int g = lane >> 4, c16 = lane & 15;
  const int s = cnt[node] + bsum[node >> 10];
  const int e = (node + 1 < N_NODES) ? (cnt[node + 1] + bsum[(node + 1) >> 10]) : N_EDGES;
  const int deg = e - s;

  float a[8] = {0.f, 0.f, 0.f, 0.f, 0.f, 0.f, 0.f, 0.f};
  if (deg > 0) {
    const int* bucket = eidx + s;
    const int nit = (deg + 3) >> 2;
    int j = g;
    int ecur = bucket[(j < deg) ? j : 0];
    bool vcur = (j < deg);
    for (int it = 0; it < nit; ++it) {
      int jn = j + 4;
      int enext = bucket[(jn < deg) ? jn : 0];
      bf16x8 v = ld8(h + (long)ecur * 128 + c16 * 8);
#pragma unroll
      for (int k = 0; k < 8; ++k) a[k] += vcur ? (float)v[k] : 0.f;
      ecur = enext; vcur = (jn < deg); j = jn;
    }
  }
#pragma unroll
  for (int k = 0; k < 8; ++k) {
    a[k] += __shfl_xor(a[k], 16, 64);
    a[k] += __shfl_xor(a[k], 32, 64);
  }
  if (g == 0) {
    bf16x8 o;
#pragma unroll
    for (int k = 0; k < 8; ++k) o[k] = (__bf16)a[k];
    st8(aggbf + (long)node * 128 + c16 * 8, o);
  }
}

// ---- node GEMM: outf[n] = A[n] @ BT + bias  (f32 out, no relu) ----
// used for q = nf @ Wi[0:128] + bi  (ldb=160) and gW = agg @ Wu + bu (ldb=128)
__global__ __launch_bounds__(256) void k_nodegemm(
    const __bf16* __restrict__ A, const __bf16* __restrict__ BT, const int ldb,
    const float* __restrict__ bias, float* __restrict__ outf, const int nrows)
{
  const int tid = threadIdx.x;
  const int lane = tid & 63, wave = tid >> 6;
  const int l15 = lane & 15, quad = lane >> 4;
  const int wm = wave >> 1, wn = wave & 1;
  const int base = blockIdx.x * TILE;

  int rowm[4];
#pragma unroll
  for (int ms = 0; ms < 4; ++ms) {
    int nd = base + wm * 64 + ms * 16 + l15;
    rowm[ms] = nd < nrows ? nd : (nrows - 1);
  }
  f32x4 acc[4][4] = {};
#pragma unroll
  for (int kit = 0; kit < 4; ++kit) {
    const int koff = kit * 32 + quad * 8;
    bf16x8 a[4];
#pragma unroll
    for (int ms = 0; ms < 4; ++ms)
      a[ms] = ld8(A + (long)rowm[ms] * 128 + koff);
#pragma unroll
    for (int ns = 0; ns < 4; ++ns) {
      bf16x8 b = ld8(BT + (wn * 64 + ns * 16 + l15) * ldb + koff);
#pragma unroll
      for (int ms = 0; ms < 4; ++ms)
        acc[ms][ns] = __builtin_amdgcn_mfma_f32_16x16x32_bf16(a[ms], b, acc[ms][ns], 0, 0, 0);
    }
  }
#pragma unroll
  for (int ns = 0; ns < 4; ++ns) {
    const int col = wn * 64 + ns * 16 + l15;
    const float bv = bias[col];
#pragma unroll
    for (int ms = 0; ms < 4; ++ms) {
      const int r0 = wm * 64 + ms * 16 + quad * 4;
#pragma unroll
      for (int r = 0; r < 4; ++r) {
        const int node = base + r0 + r;
        if (node < nrows) outf[(long)node * 128 + col] = acc[ms][ns][r] + bv;
      }
    }
  }
}

// ---- init: h0 = relu(q[src] + ef @ Wi[128:160])  (bi folded into q) ----
__global__ __launch_bounds__(256) void k_init(
    const float* __restrict__ ef, const int* __restrict__ esrc,
    const __bf16* __restrict__ WiT, const float* __restrict__ q,
    __bf16* __restrict__ h)
{
  __shared__ __align__(16) char smem[32768];
  float*  efT  = (float*)smem;    // [128][32] f32, 16B-chunk XOR swizzle (8 chunks/row)
  __bf16* cbuf = (__bf16*)smem;   // reused after MFMA loop
  const int tid = threadIdx.x;
  const int lane = tid & 63, wave = tid >> 6;
  const int l15 = lane & 15, quad = lane >> 4;
  const int wm = wave >> 1, wn = wave & 1;
  const long base = (long)blockIdx.x * TILE;

  // async-stage ef tile (f32): 4 instrs/wave, 8 rows each
#pragma unroll
  for (int j = 0; j < 4; ++j) {
    const int r = wave * 32 + j * 8 + (lane >> 3);
    const int cd = (lane & 7) ^ (r & 7);
    async16(ef + (base + r) * 32 + cd * 4, efT + (wave * 32 + j * 8) * 32);
  }
  __syncthreads();

  f32x4 acc[4][4] = {};
  // single K=32 pass vs Wi bottom slice
  {
    bf16x8 a[4];
#pragma unroll
    for (int ms = 0; ms < 4; ++ms) {
      const int rm = wm * 64 + ms * 16 + l15;
      const int c0 = (quad * 2) ^ (rm & 7);
      f32x4 f0 = *(const f32x4*)(efT + rm * 32 + c0 * 4);
      f32x4 f1 = *(const f32x4*)(efT + rm * 32 + (c0 ^ 1) * 4);
      bf16x8 v;
#pragma unroll
      for (int j = 0; j < 4; ++j) { v[j] = (__bf16)f0[j]; v[4 + j] = (__bf16)f1[j]; }
      a[ms] = v;
    }
#pragma unroll
    for (int ns = 0; ns < 4; ++ns) {
      bf16x8 b = ld8(WiT + (wn * 64 + ns * 16 + l15) * 160 + 128 + quad * 8);
#pragma unroll
      for (int ms = 0; ms < 4; ++ms)
        acc[ms][ns] = __builtin_amdgcn_mfma_f32_16x16x32_bf16(a[ms], b, acc[ms][ns], 0, 0, 0);
    }
  }

  const int c15 = tid & 15, rbase = tid >> 4;
  int srcv[8];
#pragma unroll
  for (int i = 0; i < 8; ++i) srcv[i] = esrc[base + i * 16 + rbase];

  __syncthreads();
  // C write, 16B-chunk XOR swizzled (no bias)
#pragma unroll
  for (int ns = 0; ns < 4; ++ns) {
    const int col = wn * 64 + ns * 16 + l15;
#pragma unroll
    for (int ms = 0; ms < 4; ++ms) {
      const int r0 = wm * 64 + ms * 16 + quad * 4;
#pragma unroll
      for (int r = 0; r < 4; ++r) {
        const int row = r0 + r;
        cbuf[row * 128 + (((col >> 3) ^ (row & 15)) * 8) + (col & 7)] = (__bf16)acc[ms][ns][r];
      }
    }
  }
  __syncthreads();

  f32x4 g0 = *(const f32x4*)(q + (long)srcv[0] * 128 + c15 * 8);
  f32x4 g1 = *(const f32x4*)(q + (long)srcv[0] * 128 + c15 * 8 + 4);
#pragma unroll
  for (int i = 0; i < 8; ++i) {
    f32x4 ng0, ng1;
    if (i < 7) {
      const float* gp = q + (long)srcv[i + 1] * 128 + c15 * 8;
      ng0 = *(const f32x4*)gp; ng1 = *(const f32x4*)(gp + 4);
    }
    const int row = i * 16 + rbase;
    bf16x8 cv = ld8(cbuf + row * 128 + ((c15 ^ (row & 15)) * 8));
    bf16x8 o;
#pragma unroll
    for (int j = 0; j < 8; ++j) {
      float gj = (j < 4) ? g0[j] : g1[j - 4];
      float v = gj + (float)cv[j];
      v = v > 0.f ? v : 0.f;
      o[j] = (__bf16)v;
    }
    st8(h + (base + row) * 128 + c15 * 8, o);
    g0 = ng0; g1 = ng1;
  }
}

// ---- update: h[e] = relu(gW[src[e]] - (h@Wu)[e^1] + h[e])  (bu folded into gW) ----
__global__ __launch_bounds__(256) void k_update(
    __bf16* __restrict__ h, const int* __restrict__ esrc,
    const __bf16* __restrict__ WuT, const float* __restrict__ gW)
{
  __shared__ __align__(16) __bf16 smem[128 * 128];  // hT staged, then C roundtrip
  const int tid = threadIdx.x;
  const int lane = tid & 63, wave = tid >> 6;
  const int l15 = lane & 15, quad = lane >> 4;
  const int wm = wave >> 1, wn = wave & 1;
  const long base = (long)blockIdx.x * TILE;

  // async-stage h tile, 16B-chunk XOR swizzle: 8 instrs/wave, 4 rows each
#pragma unroll
  for (int j = 0; j < 8; ++j) {
    const int r = wave * 32 + j * 4 + (lane >> 4);
    const int cd = (lane & 15) ^ (r & 15);
    async16(h + (base + r) * 128 + cd * 8, smem + (wave * 32 + j * 4) * 128);
  }
  __syncthreads();

  // P = h_tile @ Wu (straight rows; rev applied at C readback)
  f32x4 acc[4][4] = {};
#pragma unroll
  for (int kit = 0; kit < 4; ++kit) {
    bf16x8 a[4];
#pragma unroll
    for (int ms = 0; ms < 4; ++ms) {
      const int rm = wm * 64 + ms * 16 + l15;
      a[ms] = ld8(smem + rm * 128 + (((kit * 4 + quad) ^ l15) * 8));
    }
#pragma unroll
    for (int ns = 0; ns < 4; ++ns) {
      bf16x8 b = ld8(WuT + (wn * 64 + ns * 16 + l15) * 128 + kit * 32 + quad * 8);
#pragma unroll
      for (int ms = 0; ms < 4; ++ms)
        acc[ms][ns] = __builtin_amdgcn_mfma_f32_16x16x32_bf16(a[ms], b, acc[ms][ns], 0, 0, 0);
    }
  }

  // residual + src preload (before smem is overwritten by C)
  const int c15 = tid & 15, rbase = tid >> 4;
  bf16x8 hv[8];
  int srcv[8];
#pragma unroll
  for (int i = 0; i < 8; ++i) {
    const int row = i * 16 + rbase;
    hv[i] = ld8(smem + row * 128 + ((c15 ^ (row & 15)) * 8));
    srcv[i] = esrc[base + row];
  }
  __syncthreads();
  // C write, swizzled (no bias)
#pragma unroll
  for (int ns = 0; ns < 4; ++ns) {
    const int col = wn * 64 + ns * 16 + l15;
#pragma unroll
    for (int ms = 0; ms < 4; ++ms) {
      const int r0 = wm * 64 + ms * 16 + quad * 4;
#pragma unroll
      for (int r = 0; r < 4; ++r) {
        const int row = r0 + r;
        smem[row * 128 + (((col >> 3) ^ (row & 15)) * 8) + (col & 7)] = (__bf16)acc[ms][ns][r];
      }
    }
  }
  __syncthreads();

  f32x4 g0 = *(const f32x4*)(gW + (long)srcv[0] * 128 + c15 * 8);
  f32x4 g1 = *(const f32x4*)(gW + (long)srcv[0] * 128 + c15 * 8 + 4);
#pragma unroll
  for (int i = 0; i < 8; ++i) {
    f32x4 ng0, ng1;
    if (i < 7) {
      const float* gp = gW + (long)srcv[i + 1] * 128 + c15 * 8;
      ng0 = *(const f32x4*)gp; ng1 = *(const f32x4*)(gp + 4);
    }
    const int row = i * 16 + rbase;
    const int rowr = row ^ 1;  // rev(e) = e^1, pair-aligned within tile
    bf16x8 cv = ld8(smem + rowr * 128 + ((c15 ^ (rowr & 15)) * 8));
    bf16x8 o;
#pragma unroll
    for (int j = 0; j < 8; ++j) {
      float gj = (j < 4) ? g0[j] : g1[j - 4];
      float v = gj - (float)cv[j] + (float)hv[i][j];
      v = v > 0.f ? v : 0.f;
      o[j] = (__bf16)v;
    }
    st8(h + (base + row) * 128 + c15 * 8, o);
    g0 = ng0; g1 = ng1;
  }
}

// ---- final: out = relu([nf | agg(h4)] @ Wf + bf) over nodes ----
__global__ __launch_bounds__(256) void k_final(
    const __bf16* __restrict__ nfbf, const __bf16* __restrict__ aggbf,
    const __bf16* __restrict__ WfT, const float* __restrict__ bfb,
    float* __restrict__ out)
{
  const int tid = threadIdx.x;
  const int lane = tid & 63, wave = tid >> 6;
  const int l15 = lane & 15, quad = lane >> 4;
  const int wm = wave >> 1, wn = wave & 1;
  const int base = blockIdx.x * TILE;

  int nodem[4];
#pragma unroll
  for (int ms = 0; ms < 4; ++ms) {
    int nd = base + wm * 64 + ms * 16 + l15;
    nodem[ms] = nd < N_NODES ? nd : (N_NODES - 1);
  }
  f32x4 acc[4][4] = {};
#pragma unroll
  for (int kit = 0; kit < 8; ++kit) {
    const int koff = kit * 32 + quad * 8;
    bf16x8 a[4];
#pragma unroll
    for (int ms = 0; ms < 4; ++ms)
      a[ms] = (kit < 4) ? ld8(nfbf + (long)nodem[ms] * 128 + koff)
                        : ld8(aggbf + (long)nodem[ms] * 128 + (koff - 128));
#pragma unroll
    for (int ns = 0; ns < 4; ++ns) {
      bf16x8 b = ld8(WfT + (wn * 64 + ns * 16 + l15) * 256 + koff);
#pragma unroll
      for (int ms = 0; ms < 4; ++ms)
        acc[ms][ns] = __builtin_amdgcn_mfma_f32_16x16x32_bf16(a[ms], b, acc[ms][ns], 0, 0, 0);
    }
  }
#pragma unroll
  for (int ns = 0; ns < 4; ++ns) {
    const int col = wn * 64 + ns * 16 + l15;
    const float bias = bfb[col];
#pragma unroll
    for (int ms = 0; ms < 4; ++ms) {
      const int r0 = wm * 64 + ms * 16 + quad * 4;
#pragma unroll
      for (int r = 0; r < 4; ++r) {
        const int node = base + r0 + r;
        if (node < N_NODES) {
          float v = acc[ms][ns][r] + bias;
          out[(long)node * 128 + col] = v > 0.f ? v : 0.f;
        }
      }
    }
  }
}

extern "C" void kernel_launch(void* const* d_in, const int* in_sizes, int n_in,
                              void* d_out, int out_size, void* d_ws, size_t ws_size,
                              hipStream_t stream) {
  const float* nf   = (const float*)d_in[0];
  const float* ef   = (const float*)d_in[1];
  const int*   esrc = (const int*)d_in[2];
  const int*   edst = (const int*)d_in[3];
  const float* Wi   = (const float*)d_in[4];
  const float* bi   = (const float*)d_in[5];
  const float* Wu   = (const float*)d_in[6];
  const float* bu   = (const float*)d_in[7];
  const float* Wf   = (const float*)d_in[8];
  const float* bfb  = (const float*)d_in[9];
  float* out = (float*)d_out;

  char* ws = (char*)d_ws;
  __bf16* h      = (__bf16*)(ws);                  // 409,600,000 B
  __bf16* aggbf  = (__bf16*)(ws + 409600000L);     //  12,800,000 B
  __bf16* nfbf   = (__bf16*)(ws + 422400000L);     //  12,800,000 B
  __bf16* WiT    = (__bf16*)(ws + 435200000L);     //      40,960 B
  __bf16* WuT    = (__bf16*)(ws + 435240960L);     //      32,768 B
  __bf16* WfT    = (__bf16*)(ws + 435273728L);     //      65,536 B
  int*    cnt    = (int*)(ws + 435339264L);        //     200,000 B
  int*    cursor = (int*)(ws + 435539264L);        //     200,000 B
  int*    bsum   = (int*)(ws + 435739264L);        //         256 B
  int*    eidx   = (int*)(ws + 435739520L);        //   6,400,000 B
  float*  g      = (float*)(ws + 442139520L);      //  25,600,000 B (q then gW; end 467,739,520)

  const long NV = (long)N_NODES * 128;
  const int  NGB = (N_NODES + TILE - 1) / TILE;    // 391

  hipLaunchKernelGGL(k_prep_w, dim3(272), dim3(256), 0, stream, Wi, Wu, Wf, WiT, WuT, WfT);
  hipLaunchKernelGGL(k_cvt, dim3(3125), dim3(256), 0, stream, nf, nfbf, NV);
  // CSR build
  hipMemsetAsync(cnt, 0, 200000, stream);
  hipLaunchKernelGGL(k_hist, dim3(N_EDGES / 256), dim3(256), 0, stream, edst, cnt);
  hipLaunchKernelGGL(k_scan1, dim3(49), dim3(1024), 0, stream, cnt, bsum, N_NODES);
  hipLaunchKernelGGL(k_scan2, dim3(1), dim3(64), 0, stream, bsum, 49);
  hipLaunchKernelGGL(k_scan3, dim3(196), dim3(256), 0, stream, cnt, bsum, cursor, N_NODES);
  hipLaunchKernelGGL(k_fill, dim3(N_EDGES / 256), dim3(256), 0, stream, edst, cursor, eidx);

  // q = nf @ Wi[0:128] + bi (per node), then per-edge init with K=32 ef slice
  hipLaunchKernelGGL(k_nodegemm, dim3(NGB), dim3(256), 0, stream, nfbf, WiT, 160, bi, g, N_NODES);
  hipLaunchKernelGGL(k_init, dim3(N_EDGES / TILE), dim3(256), 0, stream, ef, esrc, WiT, g, h);

  for (int t = 0; t < 4; ++t) {
    hipLaunchKernelGGL(k_agg, dim3(N_NODES / 4), dim3(256), 0, stream, h, cnt, bsum, eidx, aggbf);
    hipLaunchKernelGGL(k_nodegemm, dim3(NGB), dim3(256), 0, stream, aggbf, WuT, 128, bu, g, N_NODES);
    hipLaunchKernelGGL(k_update, dim3(N_EDGES / TILE), dim3(256), 0, stream, h, esrc, WuT, g);
  }
  hipLaunchKernelGGL(k_agg, dim3(N_NODES / 4), dim3(256), 0, stream, h, cnt, bsum, eidx, aggbf);
  hipLaunchKernelGGL(k_final, dim3(NGB), dim3(256), 0, stream, nfbf, aggbf, WfT, bfb, out);
}

// Round 5
// 2174.893 us; speedup vs baseline: 2.2366x; 1.1104x over previous
//
#include <hip/hip_runtime.h>
#include <hip/hip_bf16.h>

#define N_NODES 50000
#define N_EDGES 1600000
#define TILE    128

typedef __bf16 bf16x8 __attribute__((ext_vector_type(8)));
typedef float  f32x4  __attribute__((ext_vector_type(4)));

static __device__ __forceinline__ bf16x8 ld8(const __bf16* p) {
  return *reinterpret_cast<const bf16x8*>(p);
}
static __device__ __forceinline__ void st8(__bf16* p, bf16x8 v) {
  *reinterpret_cast<bf16x8*>(p) = v;
}

// async global->LDS DMA, 16B per lane; dest = wave-uniform base + lane*16
static __device__ __forceinline__ void async16(const void* g, void* l) {
  auto gp = (const __attribute__((address_space(1))) unsigned int*)(unsigned long long)g;
  auto lp = (__attribute__((address_space(3))) unsigned int*)(unsigned int)(unsigned long long)l;
  __builtin_amdgcn_global_load_lds(gp, lp, 16, 0, 0);
}

// ---- prep: transpose weights to [n][k] bf16 (B-operand layout) ----
__global__ __launch_bounds__(256) void k_prep_w(
    const float* __restrict__ Wi, const float* __restrict__ Wu,
    const float* __restrict__ Wf,
    __bf16* __restrict__ WiT, __bf16* __restrict__ WuT, __bf16* __restrict__ WfT)
{
  int g = blockIdx.x * 256 + threadIdx.x;
  if (g < 160 * 128) {
    int n = g / 160, k = g % 160;
    WiT[g] = (__bf16)Wi[k * 128 + n];
  } else if (g < 160 * 128 + 128 * 128) {
    int gg = g - 160 * 128;
    int n = gg / 128, k = gg % 128;
    WuT[gg] = (__bf16)Wu[k * 128 + n];
  } else if (g < 160 * 128 + 128 * 128 + 256 * 128) {
    int gg = g - (160 * 128 + 128 * 128);
    int n = gg / 256, k = gg % 256;
    WfT[gg] = (__bf16)Wf[k * 128 + n];
  }
}

// ---- f32 -> bf16 bulk convert ----
__global__ __launch_bounds__(256) void k_cvt(
    const float* __restrict__ in, __bf16* __restrict__ out, long n)
{
  long i = ((long)blockIdx.x * 256 + threadIdx.x) * 8;
  if (i + 8 <= n) {
    f32x4 f0 = *(const f32x4*)(in + i);
    f32x4 f1 = *(const f32x4*)(in + i + 4);
    bf16x8 o;
#pragma unroll
    for (int j = 0; j < 4; ++j) { o[j] = (__bf16)f0[j]; o[4 + j] = (__bf16)f1[j]; }
    st8(out + i, o);
  }
}

// ---- CSR build ----
__global__ __launch_bounds__(256) void k_hist(
    const int* __restrict__ edst, int* __restrict__ cnt)
{
  int e = blockIdx.x * 256 + threadIdx.x;
  if (e < N_EDGES) atomicAdd(&cnt[edst[e]], 1);
}

__global__ __launch_bounds__(1024) void k_scan1(
    int* __restrict__ cnt, int* __restrict__ bsum, int n)
{
  __shared__ int sm[1024];
  const int tid = threadIdx.x;
  int i = blockIdx.x * 1024 + tid;
  int v = (i < n) ? cnt[i] : 0;
  sm[tid] = v;
  __syncthreads();
  for (int off = 1; off < 1024; off <<= 1) {
    int t = (tid >= off) ? sm[tid - off] : 0;
    __syncthreads();
    sm[tid] += t;
    __syncthreads();
  }
  if (i < n) cnt[i] = sm[tid] - v;
  if (tid == 1023) bsum[blockIdx.x] = sm[1023];
}

__global__ __launch_bounds__(64) void k_scan2(int* __restrict__ bsum, int nb)
{
  if (threadIdx.x == 0) {
    int acc = 0;
    for (int k = 0; k < nb; ++k) { int t = bsum[k]; bsum[k] = acc; acc += t; }
  }
}

__global__ __launch_bounds__(256) void k_scan3(
    const int* __restrict__ cnt, const int* __restrict__ bsum,
    int* __restrict__ cursor, int n)
{
  int i = blockIdx.x * 256 + threadIdx.x;
  if (i < n) cursor[i] = cnt[i] + bsum[i >> 10];
}

__global__ __launch_bounds__(256) void k_fill(
    const int* __restrict__ edst, int* __restrict__ cursor, int* __restrict__ eidx)
{
  int e = blockIdx.x * 256 + threadIdx.x;
  if (e < N_EDGES) {
    int p = atomicAdd(&cursor[edst[e]], 1);
    eidx[p] = e;
  }
}

// ---- gather-aggregate: aggbf[n] = sum over incoming edges h[e] ----
// one wave per node; 8 lane-groups of 8 lanes, 32B/lane -> 8 rows (2KB) in
// flight per wave; edge-index pipeline 2-deep to break idx->row dependence.
__global__ __launch_bounds__(256) void k_agg(
    const __bf16* __restrict__ h, const int* __restrict__ cnt,
    const int* __restrict__ bsum, const int* __restrict__ eidx,
    __bf16* __restrict__ aggbf)
{
  const int wave = threadIdx.x >> 6;
  const int node = blockIdx.x * 4 + wave;
  const int lane = threadIdx.x & 63;
  const int g = lane >> 3, c8 = lane & 7;
  const int s = cnt[node] + bsum[node >> 10];
  const int e = (node + 1 < N_NODES) ? (cnt[node + 1] + bsum[(node + 1) >> 10]) : N_EDGES;
  const int deg = e - s;

  float a[16] = {};
  if (deg > 0) {
    const int* bucket = eidx + s;
    const int nit = (deg + 7) >> 3;
    int j0 = g;
    int e0 = bucket[(j0 < deg) ? j0 : 0];
    int e1 = bucket[(j0 + 8 < deg) ? j0 + 8 : 0];
    bool v0 = (j0 < deg), v1 = (j0 + 8 < deg);
    for (int it = 0; it < nit; ++it) {
      const int j2 = j0 + 16;
      const int e2 = bucket[(j2 < deg) ? j2 : 0];
      const __bf16* hp = h + (long)e0 * 128 + c8 * 16;
      bf16x8 r0 = ld8(hp), r1 = ld8(hp + 8);
#pragma unroll
      for (int k = 0; k < 8; ++k) {
        a[k]     += v0 ? (float)r0[k] : 0.f;
        a[8 + k] += v0 ? (float)r1[k] : 0.f;
      }
      e0 = e1; v0 = v1;
      e1 = e2; v1 = (j2 < deg);
      j0 += 8;
    }
  }
#pragma unroll
  for (int k = 0; k < 16; ++k) {
    a[k] += __shfl_xor(a[k], 8, 64);
    a[k] += __shfl_xor(a[k], 16, 64);
    a[k] += __shfl_xor(a[k], 32, 64);
  }
  if (g == 0) {
    bf16x8 o0, o1;
#pragma unroll
    for (int k = 0; k < 8; ++k) { o0[k] = (__bf16)a[k]; o1[k] = (__bf16)a[8 + k]; }
    st8(aggbf + (long)node * 128 + c8 * 16, o0);
    st8(aggbf + (long)node * 128 + c8 * 16 + 8, o1);
  }
}

// ---- node GEMM: outb[n] = bf16(A[n] @ BT + bias)  (no relu) ----
// q = nf @ Wi[0:128] + bi (ldb=160); gW = agg @ Wu + bu (ldb=128)
__global__ __launch_bounds__(256) void k_nodegemm(
    const __bf16* __restrict__ A, const __bf16* __restrict__ BT, const int ldb,
    const float* __restrict__ bias, __bf16* __restrict__ outb, const int nrows)
{
  const int tid = threadIdx.x;
  const int lane = tid & 63, wave = tid >> 6;
  const int l15 = lane & 15, quad = lane >> 4;
  const int wm = wave >> 1, wn = wave & 1;
  const int base = blockIdx.x * TILE;

  int rowm[4];
#pragma unroll
  for (int ms = 0; ms < 4; ++ms) {
    int nd = base + wm * 64 + ms * 16 + l15;
    rowm[ms] = nd < nrows ? nd : (nrows - 1);
  }
  f32x4 acc[4][4] = {};
#pragma unroll
  for (int kit = 0; kit < 4; ++kit) {
    const int koff = kit * 32 + quad * 8;
    bf16x8 a[4];
#pragma unroll
    for (int ms = 0; ms < 4; ++ms)
      a[ms] = ld8(A + (long)rowm[ms] * 128 + koff);
#pragma unroll
    for (int ns = 0; ns < 4; ++ns) {
      bf16x8 b = ld8(BT + (wn * 64 + ns * 16 + l15) * ldb + koff);
#pragma unroll
      for (int ms = 0; ms < 4; ++ms)
        acc[ms][ns] = __builtin_amdgcn_mfma_f32_16x16x32_bf16(a[ms], b, acc[ms][ns], 0, 0, 0);
    }
  }
#pragma unroll
  for (int ns = 0; ns < 4; ++ns) {
    const int col = wn * 64 + ns * 16 + l15;
    const float bv = bias[col];
#pragma unroll
    for (int ms = 0; ms < 4; ++ms) {
      const int r0 = wm * 64 + ms * 16 + quad * 4;
#pragma unroll
      for (int r = 0; r < 4; ++r) {
        const int node = base + r0 + r;
        if (node < nrows) outb[(long)node * 128 + col] = (__bf16)(acc[ms][ns][r] + bv);
      }
    }
  }
}

// ---- init: h0 = relu(q[src] + ef @ Wi[128:160])  (bi folded into q, q bf16) ----
__global__ __launch_bounds__(256) void k_init(
    const float* __restrict__ ef, const int* __restrict__ esrc,
    const __bf16* __restrict__ WiT, const __bf16* __restrict__ q,
    __bf16* __restrict__ h)
{
  __shared__ __align__(16) char smem[32768];
  float*  efT  = (float*)smem;    // [128][32] f32, 16B-chunk XOR swizzle
  __bf16* cbuf = (__bf16*)smem;   // reused after MFMA loop
  const int tid = threadIdx.x;
  const int lane = tid & 63, wave = tid >> 6;
  const int l15 = lane & 15, quad = lane >> 4;
  const int wm = wave >> 1, wn = wave & 1;
  const long base = (long)blockIdx.x * TILE;

#pragma unroll
  for (int j = 0; j < 4; ++j) {
    const int r = wave * 32 + j * 8 + (lane >> 3);
    const int cd = (lane & 7) ^ (r & 7);
    async16(ef + (base + r) * 32 + cd * 4, efT + (wave * 32 + j * 8) * 32);
  }
  __syncthreads();

  f32x4 acc[4][4] = {};
  {
    bf16x8 a[4];
#pragma unroll
    for (int ms = 0; ms < 4; ++ms) {
      const int rm = wm * 64 + ms * 16 + l15;
      const int c0 = (quad * 2) ^ (rm & 7);
      f32x4 f0 = *(const f32x4*)(efT + rm * 32 + c0 * 4);
      f32x4 f1 = *(const f32x4*)(efT + rm * 32 + (c0 ^ 1) * 4);
      bf16x8 v;
#pragma unroll
      for (int j = 0; j < 4; ++j) { v[j] = (__bf16)f0[j]; v[4 + j] = (__bf16)f1[j]; }
      a[ms] = v;
    }
#pragma unroll
    for (int ns = 0; ns < 4; ++ns) {
      bf16x8 b = ld8(WiT + (wn * 64 + ns * 16 + l15) * 160 + 128 + quad * 8);
#pragma unroll
      for (int ms = 0; ms < 4; ++ms)
        acc[ms][ns] = __builtin_amdgcn_mfma_f32_16x16x32_bf16(a[ms], b, acc[ms][ns], 0, 0, 0);
    }
  }

  const int c15 = tid & 15, rbase = tid >> 4;
  int srcv[8];
#pragma unroll
  for (int i = 0; i < 8; ++i) srcv[i] = esrc[base + i * 16 + rbase];
  // start the gather pipeline before the C-write barrier (hides latency)
  bf16x8 gp0 = ld8(q + (long)srcv[0] * 128 + c15 * 8);
  bf16x8 gp1 = ld8(q + (long)srcv[1] * 128 + c15 * 8);

  __syncthreads();
#pragma unroll
  for (int ns = 0; ns < 4; ++ns) {
    const int col = wn * 64 + ns * 16 + l15;
#pragma unroll
    for (int ms = 0; ms < 4; ++ms) {
      const int r0 = wm * 64 + ms * 16 + quad * 4;
#pragma unroll
      for (int r = 0; r < 4; ++r) {
        const int row = r0 + r;
        cbuf[row * 128 + (((col >> 3) ^ (row & 15)) * 8) + (col & 7)] = (__bf16)acc[ms][ns][r];
      }
    }
  }
  __syncthreads();

#pragma unroll
  for (int i = 0; i < 8; ++i) {
    bf16x8 gnext;
    if (i < 6) gnext = ld8(q + (long)srcv[i + 2] * 128 + c15 * 8);
    const int row = i * 16 + rbase;
    bf16x8 cv = ld8(cbuf + row * 128 + ((c15 ^ (row & 15)) * 8));
    bf16x8 o;
#pragma unroll
    for (int j = 0; j < 8; ++j) {
      float v = (float)gp0[j] + (float)cv[j];
      v = v > 0.f ? v : 0.f;
      o[j] = (__bf16)v;
    }
    st8(h + (base + row) * 128 + c15 * 8, o);
    gp0 = gp1; gp1 = gnext;
  }
}

// ---- update: h[e] = relu(gW[src[e]] - (h@Wu)[e^1] + h[e])  (bu in gW, bf16) ----
__global__ __launch_bounds__(256) void k_update(
    __bf16* __restrict__ h, const int* __restrict__ esrc,
    const __bf16* __restrict__ WuT, const __bf16* __restrict__ gW)
{
  __shared__ __align__(16) __bf16 smem[128 * 128];  // h staged, then C roundtrip
  const int tid = threadIdx.x;
  const int lane = tid & 63, wave = tid >> 6;
  const int l15 = lane & 15, quad = lane >> 4;
  const int wm = wave >> 1, wn = wave & 1;
  const long base = (long)blockIdx.x * TILE;

#pragma unroll
  for (int j = 0; j < 8; ++j) {
    const int r = wave * 32 + j * 4 + (lane >> 4);
    const int cd = (lane & 15) ^ (r & 15);
    async16(h + (base + r) * 128 + cd * 8, smem + (wave * 32 + j * 4) * 128);
  }
  __syncthreads();

  f32x4 acc[4][4] = {};
#pragma unroll
  for (int kit = 0; kit < 4; ++kit) {
    bf16x8 a[4];
#pragma unroll
    for (int ms = 0; ms < 4; ++ms) {
      const int rm = wm * 64 + ms * 16 + l15;
      a[ms] = ld8(smem + rm * 128 + (((kit * 4 + quad) ^ l15) * 8));
    }
#pragma unroll
    for (int ns = 0; ns < 4; ++ns) {
      bf16x8 b = ld8(WuT + (wn * 64 + ns * 16 + l15) * 128 + kit * 32 + quad * 8);
#pragma unroll
      for (int ms = 0; ms < 4; ++ms)
        acc[ms][ns] = __builtin_amdgcn_mfma_f32_16x16x32_bf16(a[ms], b, acc[ms][ns], 0, 0, 0);
    }
  }

  // residual + src preload before smem is overwritten by C
  const int c15 = tid & 15, rbase = tid >> 4;
  bf16x8 hv[8];
  int srcv[8];
#pragma unroll
  for (int i = 0; i < 8; ++i) {
    const int row = i * 16 + rbase;
    hv[i] = ld8(smem + row * 128 + ((c15 ^ (row & 15)) * 8));
    srcv[i] = esrc[base + row];
  }
  // start the gW gather before the C-write barrier (hides gather latency)
  bf16x8 gp0 = ld8(gW + (long)srcv[0] * 128 + c15 * 8);
  bf16x8 gp1 = ld8(gW + (long)srcv[1] * 128 + c15 * 8);

  __syncthreads();
#pragma unroll
  for (int ns = 0; ns < 4; ++ns) {
    const int col = wn * 64 + ns * 16 + l15;
#pragma unroll
    for (int ms = 0; ms < 4; ++ms) {
      const int r0 = wm * 64 + ms * 16 + quad * 4;
#pragma unroll
      for (int r = 0; r < 4; ++r) {
        const int row = r0 + r;
        smem[row * 128 + (((col >> 3) ^ (row & 15)) * 8) + (col & 7)] = (__bf16)acc[ms][ns][r];
      }
    }
  }
  __syncthreads();

#pragma unroll
  for (int i = 0; i < 8; ++i) {
    bf16x8 gnext;
    if (i < 6) gnext = ld8(gW + (long)srcv[i + 2] * 128 + c15 * 8);
    const int row = i * 16 + rbase;
    const int rowr = row ^ 1;  // rev(e) = e^1, pair-aligned within tile
    bf16x8 cv = ld8(smem + rowr * 128 + ((c15 ^ (rowr & 15)) * 8));
    bf16x8 o;
#pragma unroll
    for (int j = 0; j < 8; ++j) {
      float v = (float)gp0[j] - (float)cv[j] + (float)hv[i][j];
      v = v > 0.f ? v : 0.f;
      o[j] = (__bf16)v;
    }
    st8(h + (base + row) * 128 + c15 * 8, o);
    gp0 = gp1; gp1 = gnext;
  }
}

// ---- final: out = relu([nf | agg(h4)] @ Wf + bf) over nodes ----
__global__ __launch_bounds__(256) void k_final(
    const __bf16* __restrict__ nfbf, const __bf16* __restrict__ aggbf,
    const __bf16* __restrict__ WfT, const float* __restrict__ bfb,
    float* __restrict__ out)
{
  const int tid = threadIdx.x;
  const int lane = tid & 63, wave = tid >> 6;
  const int l15 = lane & 15, quad = lane >> 4;
  const int wm = wave >> 1, wn = wave & 1;
  const int base = blockIdx.x * TILE;

  int nodem[4];
#pragma unroll
  for (int ms = 0; ms < 4; ++ms) {
    int nd = base + wm * 64 + ms * 16 + l15;
    nodem[ms] = nd < N_NODES ? nd : (N_NODES - 1);
  }
  f32x4 acc[4][4] = {};
#pragma unroll
  for (int kit = 0; kit < 8; ++kit) {
    const int koff = kit * 32 + quad * 8;
    bf16x8 a[4];
#pragma unroll
    for (int ms = 0; ms < 4; ++ms)
      a[ms] = (kit < 4) ? ld8(nfbf + (long)nodem[ms] * 128 + koff)
                        : ld8(aggbf + (long)nodem[ms] * 128 + (koff - 128));
#pragma unroll
    for (int ns = 0; ns < 4; ++ns) {
      bf16x8 b = ld8(WfT + (wn * 64 + ns * 16 + l15) * 256 + koff);
#pragma unroll
      for (int ms = 0; ms < 4; ++ms)
        acc[ms][ns] = __builtin_amdgcn_mfma_f32_16x16x32_bf16(a[ms], b, acc[ms][ns], 0, 0, 0);
    }
  }
#pragma unroll
  for (int ns = 0; ns < 4; ++ns) {
    const int col = wn * 64 + ns * 16 + l15;
    const float bias = bfb[col];
#pragma unroll
    for (int ms = 0; ms < 4; ++ms) {
      const int r0 = wm * 64 + ms * 16 + quad * 4;
#pragma unroll
      for (int r = 0; r < 4; ++r) {
        const int node = base + r0 + r;
        if (node < N_NODES) {
          float v = acc[ms][ns][r] + bias;
          out[(long)node * 128 + col] = v > 0.f ? v : 0.f;
        }
      }
    }
  }
}

extern "C" void kernel_launch(void* const* d_in, const int* in_sizes, int n_in,
                              void* d_out, int out_size, void* d_ws, size_t ws_size,
                              hipStream_t stream) {
  const float* nf   = (const float*)d_in[0];
  const float* ef   = (const float*)d_in[1];
  const int*   esrc = (const int*)d_in[2];
  const int*   edst = (const int*)d_in[3];
  const float* Wi   = (const float*)d_in[4];
  const float* bi   = (const float*)d_in[5];
  const float* Wu   = (const float*)d_in[6];
  const float* bu   = (const float*)d_in[7];
  const float* Wf   = (const float*)d_in[8];
  const float* bfb  = (const float*)d_in[9];
  float* out = (float*)d_out;

  char* ws = (char*)d_ws;
  __bf16* h      = (__bf16*)(ws);                  // 409,600,000 B
  __bf16* aggbf  = (__bf16*)(ws + 409600000L);     //  12,800,000 B
  __bf16* nfbf   = (__bf16*)(ws + 422400000L);     //  12,800,000 B
  __bf16* WiT    = (__bf16*)(ws + 435200000L);     //      40,960 B
  __bf16* WuT    = (__bf16*)(ws + 435240960L);     //      32,768 B
  __bf16* WfT    = (__bf16*)(ws + 435273728L);     //      65,536 B
  int*    cnt    = (int*)(ws + 435339264L);        //     200,000 B
  int*    cursor = (int*)(ws + 435539264L);        //     200,000 B
  int*    bsum   = (int*)(ws + 435739264L);        //         256 B
  int*    eidx   = (int*)(ws + 435739520L);        //   6,400,000 B
  __bf16* g      = (__bf16*)(ws + 442139520L);     //  12,800,000 B (q then gW, bf16)

  const long NV = (long)N_NODES * 128;
  const int  NGB = (N_NODES + TILE - 1) / TILE;    // 391

  hipLaunchKernelGGL(k_prep_w, dim3(272), dim3(256), 0, stream, Wi, Wu, Wf, WiT, WuT, WfT);
  hipLaunchKernelGGL(k_cvt, dim3(3125), dim3(256), 0, stream, nf, nfbf, NV);
  // CSR build
  hipMemsetAsync(cnt, 0, 200000, stream);
  hipLaunchKernelGGL(k_hist, dim3(N_EDGES / 256), dim3(256), 0, stream, edst, cnt);
  hipLaunchKernelGGL(k_scan1, dim3(49), dim3(1024), 0, stream, cnt, bsum, N_NODES);
  hipLaunchKernelGGL(k_scan2, dim3(1), dim3(64), 0, stream, bsum, 49);
  hipLaunchKernelGGL(k_scan3, dim3(196), dim3(256), 0, stream, cnt, bsum, cursor, N_NODES);
  hipLaunchKernelGGL(k_fill, dim3(N_EDGES / 256), dim3(256), 0, stream, edst, cursor, eidx);

  // q = nf @ Wi[0:128] + bi (per node, bf16), then per-edge init with K=32 ef slice
  hipLaunchKernelGGL(k_nodegemm, dim3(NGB), dim3(256), 0, stream, nfbf, WiT, 160, bi, g, N_NODES);
  hipLaunchKernelGGL(k_init, dim3(N_EDGES / TILE), dim3(256), 0, stream, ef, esrc, WiT, g, h);

  for (int t = 0; t < 4; ++t) {
    hipLaunchKernelGGL(k_agg, dim3(N_NODES / 4), dim3(256), 0, stream, h, cnt, bsum, eidx, aggbf);
    hipLaunchKernelGGL(k_nodegemm, dim3(NGB), dim3(256), 0, stream, aggbf, WuT, 128, bu, g, N_NODES);
    hipLaunchKernelGGL(k_update, dim3(N_EDGES / TILE), dim3(256), 0, stream, h, esrc, WuT, g);
  }
  hipLaunchKernelGGL(k_agg, dim3(N_NODES / 4), dim3(256), 0, stream, h, cnt, bsum, eidx, aggbf);
  hipLaunchKernelGGL(k_final, dim3(NGB), dim3(256), 0, stream, nfbf, aggbf, WfT, bfb, out);
}